// Round 1
// 1843.578 us; speedup vs baseline: 5.9026x; 5.9026x over previous
//
#include <hip/hip_runtime.h>

#define DEV __device__ __forceinline__

DEV float fast_rcp(float x) {
#if __has_builtin(__builtin_amdgcn_rcpf)
  return __builtin_amdgcn_rcpf(x);
#else
  return 1.0f / x;
#endif
}
DEV float sigm(float x) { return fast_rcp(1.0f + __expf(-x)); }
DEV float tanh_f(float x) {
  float e = __expf(-2.0f * fabsf(x));
  float t = 1.0f - 2.0f * e * fast_rcp(1.0f + e);
  return copysignf(t, x);
}
DEV float lrelu(float x) { return x > 0.0f ? x : 0.01f * x; }

DEV float wave_sum(float v) {
#pragma unroll
  for (int m = 32; m; m >>= 1) v += __shfl_xor(v, m);
  return v;
}
DEV float wave_max(float v) {
#pragma unroll
  for (int m = 32; m; m >>= 1) v = fmaxf(v, __shfl_xor(v, m));
  return v;
}
DEV float dot4(float4 w, float4 x, float acc) {
  acc = fmaf(w.x, x.x, acc);
  acc = fmaf(w.y, x.y, acc);
  acc = fmaf(w.z, x.z, acc);
  acc = fmaf(w.w, x.w, acc);
  return acc;
}

// ---------------------------------------------------------------------------
// Persistent-GRU rewrite (R4). lane = hidden unit j; wave = SPW sequences.
// Lane j computes ALL THREE gates of unit j -> no gate exchange, no shuffles,
// no barriers inside the time loop (h state lives in a wave-private LDS slice;
// within-wave ds ordering is program-order + lgkmcnt).
// Weights are LDS-resident, pre-interleaved as W3[k][j*3+g] (g = r/z/n) so a
// lane's 3 gate weights are 3 consecutive dwords; lane stride 3 is coprime
// with 32 banks -> 2 lanes/bank (free). h reads are same-address b128
// broadcasts (free).
// ---------------------------------------------------------------------------

// One 64-wide dot phase (16 quads): accumulate r/z/n partials for SPW seqs.
template <int SPW>
DEV void dot_phase16(const float* __restrict__ Wb, int koff, int j3,
                     const float* __restrict__ hbase, int hstride, int hoff,
                     float* ar, float* az, float* an) {
#pragma unroll 2
  for (int kq = 0; kq < 16; ++kq) {
    float4 hv[SPW];
#pragma unroll
    for (int s = 0; s < SPW; ++s)
      hv[s] = *(const float4*)&hbase[s * hstride + hoff + kq * 4];
#pragma unroll
    for (int c = 0; c < 4; ++c) {
      const float* wp = &Wb[(koff + kq * 4 + c) * 192 + j3];
      const float wr = wp[0], wz = wp[1], wn = wp[2];
#pragma unroll
      for (int s = 0; s < SPW; ++s) {
        const float hc = ((const float*)&hv[s])[c];
        ar[s] = fmaf(wr, hc, ar[s]);
        az[s] = fmaf(wz, hc, az[s]);
        an[s] = fmaf(wn, hc, an[s]);
      }
    }
  }
}

constexpr int ENC_W0_DW = 70 * 192;    // 13440 floats: [k=0..5]=Wih0, [6..69]=Whh0
constexpr int ENC_W1_DW = 128 * 192;   // 24576 floats: [0..63]=Wih1, [64..127]=Whh1
constexpr int ENC_SPW = 5;             // seqs per wave
constexpr int ENC_LDS = (ENC_W0_DW + ENC_W1_DW + 4 * ENC_SPW * 128) * 4;  // 162304 B

// Fused 2-layer encoder GRU. grid = 512 blocks (x 4 waves x 5 seqs = 10240),
// 1 block/CU (LDS-bound) -> exactly 2 rounds. Writes last h1 only.
__launch_bounds__(256)
__global__ void gru2_enc(const float* __restrict__ x,      // [10240][60][6]
                         const float* __restrict__ w3e0,   // [70][192]
                         const float* __restrict__ w3e1,   // [128][192]
                         const float* __restrict__ bih0, const float* __restrict__ bhh0,
                         const float* __restrict__ bih1, const float* __restrict__ bhh1,
                         float* __restrict__ h_out) {      // [10240][64]
  extern __shared__ float lds[];
  float* W0 = lds;
  float* W1 = lds + ENC_W0_DW;
  const int tid = threadIdx.x;
  const int wave = tid >> 6;
  const int j = tid & 63;
  const int j3 = j * 3;
  float* hb = lds + ENC_W0_DW + ENC_W1_DW + wave * (ENC_SPW * 128);  // [SPW][128]

  // cooperative weight load into LDS (coalesced float4)
  {
    const float4* s0 = (const float4*)w3e0;
    float4* d0 = (float4*)W0;
    for (int i = tid; i < ENC_W0_DW / 4; i += 256) d0[i] = s0[i];
    const float4* s1 = (const float4*)w3e1;
    float4* d1 = (float4*)W1;
    for (int i = tid; i < ENC_W1_DW / 4; i += 256) d1[i] = s1[i];
  }

  // per-lane biases (r,z merged; n kept split for r*hn form)
  const float br0 = bih0[j] + bhh0[j];
  const float bz0 = bih0[64 + j] + bhh0[64 + j];
  const float bxn0 = bih0[128 + j];
  const float bhn0 = bhh0[128 + j];
  const float br1 = bih1[j] + bhh1[j];
  const float bz1 = bih1[64 + j] + bhh1[64 + j];
  const float bxn1 = bih1[128 + j];
  const float bhn1 = bhh1[128 + j];

  float h0r[ENC_SPW], h1r[ENC_SPW];
#pragma unroll
  for (int s = 0; s < ENC_SPW; ++s) {
    h0r[s] = 0.0f; h1r[s] = 0.0f;
    hb[s * 128 + j] = 0.0f;
    hb[s * 128 + 64 + j] = 0.0f;
  }
  __syncthreads();  // the ONLY barrier (weights + state visible)

  const int seq0 = blockIdx.x * (4 * ENC_SPW) + wave * ENC_SPW;
  const float* xp = x + (size_t)seq0 * 360;

  for (int t = 0; t < 60; ++t) {
    // x[t] for SPW seqs: 3x float2 broadcast loads (8B-aligned), L1/L2-hit
    float xv[ENC_SPW][6];
#pragma unroll
    for (int s = 0; s < ENC_SPW; ++s) {
      const float2* q = (const float2*)(xp + s * 360 + t * 6);
      float2 a = q[0], b = q[1], c = q[2];
      xv[s][0] = a.x; xv[s][1] = a.y; xv[s][2] = b.x;
      xv[s][3] = b.y; xv[s][4] = c.x; xv[s][5] = c.y;
    }

    float ar[ENC_SPW], az[ENC_SPW], anx[ENC_SPW], anh[ENC_SPW];
#pragma unroll
    for (int s = 0; s < ENC_SPW; ++s) { ar[s] = 0.f; az[s] = 0.f; anx[s] = 0.f; anh[s] = 0.f; }

    // ---- layer0 x-part (k = 0..5)
#pragma unroll
    for (int k = 0; k < 6; ++k) {
      const float* wp = &W0[k * 192 + j3];
      const float wr = wp[0], wz = wp[1], wn = wp[2];
#pragma unroll
      for (int s = 0; s < ENC_SPW; ++s) {
        ar[s] = fmaf(wr, xv[s][k], ar[s]);
        az[s] = fmaf(wz, xv[s][k], az[s]);
        anx[s] = fmaf(wn, xv[s][k], anx[s]);
      }
    }
    // ---- layer0 h-part: h0_old = hb[s][0..63]
    dot_phase16<ENC_SPW>(W0, 6, j3, hb, 128, 0, ar, az, anh);
    // ---- layer0 epilogue: lane j owns all 3 gates of unit j
#pragma unroll
    for (int s = 0; s < ENC_SPW; ++s) {
      float r = sigm(ar[s] + br0);
      float z = sigm(az[s] + bz0);
      float n = tanh_f(anx[s] + bxn0 + r * (anh[s] + bhn0));
      float h0 = (1.0f - z) * n + z * h0r[s];
      h0r[s] = h0;
      hb[s * 128 + j] = h0;  // visible to this wave's lanes below (lgkmcnt)
    }

#pragma unroll
    for (int s = 0; s < ENC_SPW; ++s) { ar[s] = 0.f; az[s] = 0.f; anx[s] = 0.f; anh[s] = 0.f; }
    // ---- layer1 input-part over h0_new
    dot_phase16<ENC_SPW>(W1, 0, j3, hb, 128, 0, ar, az, anx);
    // ---- layer1 recurrent part over h1_old
    dot_phase16<ENC_SPW>(W1, 64, j3, hb, 128, 64, ar, az, anh);
#pragma unroll
    for (int s = 0; s < ENC_SPW; ++s) {
      float r = sigm(ar[s] + br1);
      float z = sigm(az[s] + bz1);
      float n = tanh_f(anx[s] + bxn1 + r * (anh[s] + bhn1));
      float h1 = (1.0f - z) * n + z * h1r[s];
      h1r[s] = h1;
      hb[s * 128 + 64 + j] = h1;
    }
  }

#pragma unroll
  for (int s = 0; s < ENC_SPW; ++s)
    h_out[(size_t)(seq0 + s) * 64 + j] = h1r[s];
}

// ---------------------------------------------------------------------------
// Single-layer GRU pass (I = 64) for the ALSTM. grid = 32 blocks x 4 waves x
// 4 seqs = 512. Writes full per-step h. Same wave-private structure.
// ---------------------------------------------------------------------------
constexpr int A_W_DW = 128 * 192;  // 24576
constexpr int A_SPW = 4;
constexpr int A_LDS = (A_W_DW + 4 * A_SPW * 64 * 2) * 4;  // 106496 B

__launch_bounds__(256)
__global__ void gru1(const float* __restrict__ xin,  // [N][T][64]
                     const float* __restrict__ w3,   // [128][192]
                     const float* __restrict__ bih, const float* __restrict__ bhh,
                     int T,
                     float* __restrict__ rout) {     // [N][T][64]
  extern __shared__ float lds[];
  float* W = lds;
  const int tid = threadIdx.x;
  const int wave = tid >> 6;
  const int j = tid & 63;
  const int j3 = j * 3;
  float* hb = lds + A_W_DW + wave * (A_SPW * 64);
  float* xb = lds + A_W_DW + 4 * A_SPW * 64 + wave * (A_SPW * 64);

  {
    const float4* sp = (const float4*)w3;
    float4* dp = (float4*)W;
    for (int i = tid; i < A_W_DW / 4; i += 256) dp[i] = sp[i];
  }
  const float br = bih[j] + bhh[j];
  const float bz = bih[64 + j] + bhh[64 + j];
  const float bxn = bih[128 + j];
  const float bhn = bhh[128 + j];

  float hr[A_SPW];
#pragma unroll
  for (int s = 0; s < A_SPW; ++s) { hr[s] = 0.0f; hb[s * 64 + j] = 0.0f; }
  __syncthreads();

  const int seq0 = blockIdx.x * (4 * A_SPW) + wave * A_SPW;

  for (int t = 0; t < T; ++t) {
    // wave-private coalesced stage of x_t (reads of step t-1 already done:
    // same-wave program order)
#pragma unroll
    for (int s = 0; s < A_SPW; ++s)
      xb[s * 64 + j] = xin[((size_t)(seq0 + s) * T + t) * 64 + j];

    float ar[A_SPW], az[A_SPW], anx[A_SPW], anh[A_SPW];
#pragma unroll
    for (int s = 0; s < A_SPW; ++s) { ar[s] = 0.f; az[s] = 0.f; anx[s] = 0.f; anh[s] = 0.f; }

    dot_phase16<A_SPW>(W, 0, j3, xb, 64, 0, ar, az, anx);   // input part
    dot_phase16<A_SPW>(W, 64, j3, hb, 64, 0, ar, az, anh);  // recurrent part

#pragma unroll
    for (int s = 0; s < A_SPW; ++s) {
      float r = sigm(ar[s] + br);
      float z = sigm(az[s] + bz);
      float n = tanh_f(anx[s] + bxn + r * (anh[s] + bhn));
      float h = (1.0f - z) * n + z * hr[s];
      hr[s] = h;
      hb[s * 64 + j] = h;
      rout[((size_t)(seq0 + s) * T + t) * 64 + j] = h;
    }
  }
}

// ---------------------------------------------------------------------------
// Weight interleave prep: W3[k][j*3+g] = (k<I ? Wih[g*64+j][k] : Whh[g*64+j][k-I])
// 4 sections x 8 blocks. Runs once per inference (few us).
// ---------------------------------------------------------------------------
__global__ void w3_prep(const float* __restrict__ Wih0, const float* __restrict__ Whh0,
                        const float* __restrict__ Wih1, const float* __restrict__ Whh1,
                        const float* __restrict__ aWih0, const float* __restrict__ aWhh0,
                        const float* __restrict__ aWih1, const float* __restrict__ aWhh1,
                        float* __restrict__ d_e0, float* __restrict__ d_e1,
                        float* __restrict__ d_a0, float* __restrict__ d_a1) {
  const int sec = blockIdx.x >> 3;
  const int bi = blockIdx.x & 7;
  const float* Wih; const float* Whh; float* dst; int I;
  if (sec == 0)      { Wih = Wih0;  Whh = Whh0;  dst = d_e0; I = 6; }
  else if (sec == 1) { Wih = Wih1;  Whh = Whh1;  dst = d_e1; I = 64; }
  else if (sec == 2) { Wih = aWih0; Whh = aWhh0; dst = d_a0; I = 64; }
  else               { Wih = aWih1; Whh = aWhh1; dst = d_a1; I = 64; }
  const int tot = (I + 64) * 192;
  for (int idx = bi * blockDim.x + threadIdx.x; idx < tot; idx += 8 * blockDim.x) {
    const int k = idx / 192;
    const int rem = idx - k * 192;
    const int j = rem / 3;
    const int g = rem - j * 3;
    const float v = (k < I) ? Wih[(g * 64 + j) * I + k] : Whh[(g * 64 + j) * 64 + (k - I)];
    dst[idx] = v;
  }
}

// ---------------------------------------------------------------------------
// GAT algebraic prep: v_dst[d] = sum_e trans_W[e][d]*a[e], v_src with a[64+e];
// c_dst/c_src from trans_b.  vbuf = [v_dst(64) | v_src(64) | c_dst | c_src]
// ---------------------------------------------------------------------------
__global__ void gat_prep(const float* __restrict__ tW, const float* __restrict__ tb,
                         const float* __restrict__ a, float* __restrict__ vbuf) {
  const int d = threadIdx.x;  // 64 threads
  float vd = 0.0f, vs = 0.0f;
  for (int e = 0; e < 64; ++e) {
    float w = tW[e * 64 + d];
    vd = fmaf(w, a[e], vd);
    vs = fmaf(w, a[64 + e], vs);
  }
  vbuf[d] = vd;
  vbuf[64 + d] = vs;
  if (d == 0) {
    float cd = 0.0f, cs = 0.0f;
    for (int e = 0; e < 64; ++e) {
      cd = fmaf(tb[e], a[e], cd);
      cs = fmaf(tb[e], a[64 + e], cs);
    }
    vbuf[128] = cd;
    vbuf[129] = cs;
  }
}

// s_src[n], s_dst[n] per encoder row (one wave per row)
__global__ void gat_svals(const float* __restrict__ h_enc, const float* __restrict__ vbuf,
                          float* __restrict__ s_src, float* __restrict__ s_dst) {
  const int wave = (blockIdx.x * blockDim.x + threadIdx.x) >> 6;
  const int lane = threadIdx.x & 63;
  float h = h_enc[(size_t)wave * 64 + lane];
  float pd = h * vbuf[lane];
  float ps = h * vbuf[64 + lane];
  pd = wave_sum(pd);
  ps = wave_sum(ps);
  if (lane == 0) {
    s_dst[wave] = pd + vbuf[128];
    s_src[wave] = ps + vbuf[129];
  }
}

// ---------------------------------------------------------------------------
// Dense all-pairs attention per group k (m=512): softmax_j leaky(s_i+s_j),
// weighted sum of h[k,j,:], + residual. One wave per row i; p-buffer in LDS
// (wave-private, no block barriers in the row loop); h streamed from L2.
// grid = 20 groups * 128 tiles, block = 256 (4 rows).
// ---------------------------------------------------------------------------
__launch_bounds__(256)
__global__ void gat_attn(const float* __restrict__ h_enc,
                         const float* __restrict__ s_src,
                         const float* __restrict__ s_dst,
                         float* __restrict__ hout) {
  const int k = blockIdx.x >> 7;
  const int tile = blockIdx.x & 127;
  const int wv = threadIdx.x >> 6;
  const int lane = threadIdx.x & 63;
  const int i = tile * 4 + wv;
  __shared__ float sdbuf[512];
  __shared__ __align__(16) float pbuf[4][512];

  for (int u = threadIdx.x; u < 512; u += 256) sdbuf[u] = s_dst[k * 512 + u];
  __syncthreads();

  const float si = s_src[k * 512 + i];
  float ev[8];
  float mx = -1e30f;
#pragma unroll
  for (int u = 0; u < 8; ++u) {
    ev[u] = lrelu(si + sdbuf[lane + u * 64]);
    mx = fmaxf(mx, ev[u]);
  }
  mx = wave_max(mx);
  float lsum = 0.0f;
#pragma unroll
  for (int u = 0; u < 8; ++u) {
    float p = __expf(ev[u] - mx);
    pbuf[wv][lane + u * 64] = p;
    lsum += p;
  }
  lsum = wave_sum(lsum);
  const float inv = fast_rcp(lsum);

  const float* hk = h_enc + (size_t)k * 512 * 64;
  const float4* pv = (const float4*)pbuf[wv];
  float acc0 = 0.0f, acc1 = 0.0f;
#pragma unroll 2
  for (int jj = 0; jj < 128; ++jj) {
    float4 p = pv[jj];
    const float* hp = hk + (size_t)(jj * 4) * 64 + lane;
    acc0 = fmaf(p.x, hp[0], acc0);
    acc1 = fmaf(p.y, hp[64], acc1);
    acc0 = fmaf(p.z, hp[128], acc0);
    acc1 = fmaf(p.w, hp[192], acc1);
  }
  hout[((size_t)k * 512 + i) * 64 + lane] =
      (acc0 + acc1) * inv + hk[(size_t)i * 64 + lane];
}

// ---------------------------------------------------------------------------
// Post-GAT transform: h2 = fc(hout); pred head (k==19); z = tanh(al_in(h2))
// written in [i][k][64] layout for the ALSTM scan. One wave per row.
// ---------------------------------------------------------------------------
__launch_bounds__(256)
__global__ void gat_out(const float* __restrict__ hin,
                        const float* __restrict__ fcW, const float* __restrict__ fcb,
                        const float* __restrict__ fcoW, const float* __restrict__ fcob,
                        const float* __restrict__ alinW, const float* __restrict__ alinb,
                        float* __restrict__ zout, float* __restrict__ pred) {
  const int wv = threadIdx.x >> 6;
  const int lane = threadIdx.x & 63;
  const int n = blockIdx.x * 4 + wv;  // [0,10240)
  const int k = n >> 9;
  const int i = n & 511;
  __shared__ __align__(16) float rbuf[4][64];
  __shared__ __align__(16) float rbuf2[4][64];

  float4 fw[16], aw[16];
  {
    const float4* p1 = (const float4*)(fcW + lane * 64);
    const float4* p2 = (const float4*)(alinW + lane * 64);
#pragma unroll
    for (int kk = 0; kk < 16; ++kk) fw[kk] = p1[kk];
#pragma unroll
    for (int kk = 0; kk < 16; ++kk) aw[kk] = p2[kk];
  }

  rbuf[wv][lane] = hin[(size_t)n * 64 + lane];
  float h2 = fcb[lane];
  const float4* rv = (const float4*)rbuf[wv];
#pragma unroll
  for (int kk = 0; kk < 16; ++kk) h2 = dot4(fw[kk], rv[kk], h2);

  if (k == 19) {  // pred head on last group
    float pv = lrelu(h2) * fcoW[lane];
    pv = wave_sum(pv);
    if (lane == 0) pred[i] = pv + fcob[0];
  }

  rbuf2[wv][lane] = h2;
  float zz = alinb[lane];
  const float4* rv2 = (const float4*)rbuf2[wv];
#pragma unroll
  for (int kk = 0; kk < 16; ++kk) zz = dot4(aw[kk], rv2[kk], zz);
  zout[((size_t)i * 20 + k) * 64 + lane] = tanh_f(zz);
}

// ---------------------------------------------------------------------------
// ALSTM head: scores = tanh(r @ att1.T + b1) @ att2.T, softmax over k (20),
// out_att = sum_k p_k r[:,k,:], alstm_out = [r_last ; out_att] @ al_out.T + b.
// One wave per sequence i.
// ---------------------------------------------------------------------------
__launch_bounds__(256)
__global__ void alstm_head(const float* __restrict__ r1,  // [512][20][64]
                           const float* __restrict__ W1,  // [32][64]
                           const float* __restrict__ b1,  // [32]
                           const float* __restrict__ W2,  // [32]
                           const float* __restrict__ Wo,  // [128]
                           const float* __restrict__ bo,  // [1]
                           float* __restrict__ alstm_out) {
  const int wv = threadIdx.x >> 6;
  const int lane = threadIdx.x & 63;
  const int i = blockIdx.x * 4 + wv;  // [0,512)
  const int e = lane & 31;
  __shared__ __align__(16) float rbuf[4][64];
  __shared__ float scb[4][20];

  float4 w1r[16];
  {
    const float4* p = (const float4*)(W1 + e * 64);
#pragma unroll
    for (int kk = 0; kk < 16; ++kk) w1r[kk] = p[kk];
  }
  const float b1e = b1[e];
  const float w2e = W2[e];

  for (int k = 0; k < 20; ++k) {
    rbuf[wv][lane] = r1[((size_t)i * 20 + k) * 64 + lane];
    float u = b1e;
    const float4* rp = (const float4*)rbuf[wv];
#pragma unroll
    for (int kk = 0; kk < 16; ++kk) u = dot4(w1r[kk], rp[kk], u);
    u = tanh_f(u) * w2e;
#pragma unroll
    for (int m = 16; m; m >>= 1) u += __shfl_xor(u, m);  // reduce within 32
    if (lane == 0) scb[wv][k] = u;
  }

  float mx = -1e30f;
#pragma unroll
  for (int k = 0; k < 20; ++k) mx = fmaxf(mx, scb[wv][k]);
  float p[20];
  float l = 0.0f;
#pragma unroll
  for (int k = 0; k < 20; ++k) {
    p[k] = __expf(scb[wv][k] - mx);
    l += p[k];
  }
  const float inv = fast_rcp(l);

  float oa = 0.0f, rlast = 0.0f;
#pragma unroll
  for (int k = 0; k < 20; ++k) {
    float rv = r1[((size_t)i * 20 + k) * 64 + lane];
    oa = fmaf(p[k], rv, oa);
    if (k == 19) rlast = rv;
  }
  oa *= inv;
  float v = fmaf(Wo[lane], rlast, Wo[64 + lane] * oa);
  v = wave_sum(v);
  if (lane == 0) alstm_out[i] = v + bo[0];
}

// ---------------------------------------------------------------------------
extern "C" void kernel_launch(void* const* d_in, const int* in_sizes, int n_in,
                              void* d_out, int out_size, void* d_ws, size_t ws_size,
                              hipStream_t stream) {
  const float* x      = (const float*)d_in[0];
  const float* Wih0   = (const float*)d_in[1];
  const float* Whh0   = (const float*)d_in[2];
  const float* bih0   = (const float*)d_in[3];
  const float* bhh0   = (const float*)d_in[4];
  const float* Wih1   = (const float*)d_in[5];
  const float* Whh1   = (const float*)d_in[6];
  const float* bih1   = (const float*)d_in[7];
  const float* bhh1   = (const float*)d_in[8];
  const float* transW = (const float*)d_in[9];
  const float* transb = (const float*)d_in[10];
  const float* a_vec  = (const float*)d_in[11];
  const float* fcW    = (const float*)d_in[12];
  const float* fcb    = (const float*)d_in[13];
  const float* fcoW   = (const float*)d_in[14];
  const float* fcob   = (const float*)d_in[15];
  const float* alinW  = (const float*)d_in[16];
  const float* alinb  = (const float*)d_in[17];
  const float* aWih0  = (const float*)d_in[18];
  const float* aWhh0  = (const float*)d_in[19];
  const float* abih0  = (const float*)d_in[20];
  const float* abhh0  = (const float*)d_in[21];
  const float* aWih1  = (const float*)d_in[22];
  const float* aWhh1  = (const float*)d_in[23];
  const float* abih1  = (const float*)d_in[24];
  const float* abhh1  = (const float*)d_in[25];
  const float* att1W  = (const float*)d_in[26];
  const float* att1b  = (const float*)d_in[27];
  const float* att2W  = (const float*)d_in[28];
  const float* aloutW = (const float*)d_in[29];
  const float* aloutb = (const float*)d_in[30];

  float* out = (float*)d_out;  // [0:512) alstm_out, [512:1024) pred

  float* W = (float*)d_ws;
  float* h_enc = W; W += 10240 * 64;      // also reused as r0 (steps 7-8)
  float* vbuf  = W; W += 256;
  float* s_src = W; W += 10240;
  float* s_dst = W; W += 10240;
  float* hout  = W; W += 10240 * 64;
  float* zbuf  = W; W += 512 * 20 * 64;
  float* r1    = W; W += 512 * 20 * 64;
  float* w3a0  = W; W += 24576;           // appended: +197KB over previous layout
  float* w3a1  = W; W += 24576;
  // time-disjoint aliases: w3e* live in zbuf region (zbuf written only at
  // step 6 by gat_out, w3e* consumed at step 2); r0 lives in h_enc region
  // (h_enc last read at step 5 by gat_attn).
  float* w3e0 = zbuf;
  float* w3e1 = zbuf + ENC_W0_DW;

  static bool attr_done = false;
  if (!attr_done) {
    hipFuncSetAttribute((const void*)gru2_enc,
                        hipFuncAttributeMaxDynamicSharedMemorySize, ENC_LDS);
    hipFuncSetAttribute((const void*)gru1,
                        hipFuncAttributeMaxDynamicSharedMemorySize, A_LDS);
    attr_done = true;
  }

  // 1) weight interleave prep (all 4 GRU layers)
  w3_prep<<<32, 256, 0, stream>>>(Wih0, Whh0, Wih1, Whh1, aWih0, aWhh0,
                                  aWih1, aWhh1, w3e0, w3e1, w3a0, w3a1);
  // 2) fused 2-layer persistent GRU encoder, last hidden only
  gru2_enc<<<512, 256, ENC_LDS, stream>>>(x, w3e0, w3e1, bih0, bhh0, bih1,
                                          bhh1, h_enc);
  // 3) GAT score-vector prep
  gat_prep<<<1, 64, 0, stream>>>(transW, transb, a_vec, vbuf);
  // 4) per-row s_src/s_dst
  gat_svals<<<2560, 256, 0, stream>>>(h_enc, vbuf, s_src, s_dst);
  // 5) dense attention + residual
  gat_attn<<<2560, 256, 0, stream>>>(h_enc, s_src, s_dst, hout);
  // 6) fc + pred head + ALSTM input transform (z in [i][k][64])
  gat_out<<<2560, 256, 0, stream>>>(hout, fcW, fcb, fcoW, fcob, alinW, alinb,
                                    zbuf, out + 512);
  // 7) ALSTM GRU layer 0: z -> r0 (reuses h_enc storage)
  gru1<<<32, 256, A_LDS, stream>>>(zbuf, w3a0, abih0, abhh0, 20, h_enc);
  // 8) ALSTM GRU layer 1: r0 -> r1
  gru1<<<32, 256, A_LDS, stream>>>(h_enc, w3a1, abih1, abhh1, 20, r1);
  // 9) ALSTM attention head -> alstm_out
  alstm_head<<<128, 256, 0, stream>>>(r1, att1W, att1b, att2W, aloutW, aloutb,
                                      out);
}